// Round 5
// baseline (381.828 us; speedup 1.0000x reference)
//
// Round 5: trace_fused at 4 waves/SIMD (1024 thr, 1 col-tile/wave, lb(1024,4));
// sech^2 closed form (no tanh) in trace; gemm128 with BK=64 (2 chunks/barrier).

#include <hip/hip_runtime.h>
#include <math.h>

typedef short bf8 __attribute__((ext_vector_type(8)));   // 8 bf16 = 4 VGPR
typedef float f32x4 __attribute__((ext_vector_type(4))); // MFMA acc

namespace {

constexpr float H_STEP = 1.0f / 15.0f;

__device__ inline short f2bf(float f) {  // RNE f32 -> bf16
  unsigned u = __float_as_uint(f);
  u += 0x7fffu + ((u >> 16) & 1u);
  return (short)(u >> 16);
}

__device__ inline float fast_tanh(float x) {
  const float ax = fabsf(x);
  const float e = __expf(-2.0f * ax);
  const float t = (1.0f - e) * __builtin_amdgcn_rcpf(1.0f + e);
  return copysignf(t, x);
}

// 1 - tanh(x)^2 = 4 e / (1+e)^2, e = exp(-2|x|)  (even function, no copysign)
__device__ inline float sech2(float x) {
  const float e = __expf(-2.0f * fabsf(x));
  const float r = __builtin_amdgcn_rcpf(1.0f + e);
  return 4.0f * e * r * r;
}

__device__ inline float wave_sum(float v) {
#pragma unroll
  for (int sh = 32; sh > 0; sh >>= 1) v += __shfl_xor(v, sh);
  return v;
}

// sum over each 16-lane row via DPP row_ror 1/2/4/8 (VALU-rate butterfly)
template <int CTRL>
__device__ inline float dppadd(float v) {
  return v + __int_as_float(__builtin_amdgcn_update_dpp(
                 0, __float_as_int(v), CTRL, 0xF, 0xF, true));
}
__device__ inline float red16(float v) {
  v = dppadd<0x121>(v);
  v = dppadd<0x122>(v);
  v = dppadd<0x124>(v);
  v = dppadd<0x128>(v);
  return v;
}

// async global->LDS, 16B per lane. LDS dest = wave-uniform base + lane*16.
__device__ inline void async16(const void* g, void* l) {
  __builtin_amdgcn_global_load_lds((__attribute__((address_space(1))) void*)g,
                                   (__attribute__((address_space(3))) void*)l,
                                   16, 0, 0);
}

// ---------------- converts ----------------

__global__ __launch_bounds__(256) void cvt2(const float* __restrict__ a,
                                            const float* __restrict__ b,
                                            short* __restrict__ dst, long n) {
  const long half = n >> 1;
  long i = ((long)blockIdx.x * 256 + threadIdx.x) * 4;
  const long stride = (long)gridDim.x * 1024;
  for (; i < n; i += stride) {
    const float* s = (i < half) ? (a + i) : (b + (i - half));
    const float4 f = *(const float4*)s;
    ushort4 o;
    o.x = (unsigned short)f2bf(f.x);
    o.y = (unsigned short)f2bf(f.y);
    o.z = (unsigned short)f2bf(f.z);
    o.w = (unsigned short)f2bf(f.w);
    *(ushort4*)(dst + i) = o;
  }
}

// src [K][N] f32 -> dst [N][K] bf16 (transpose + convert)
__global__ __launch_bounds__(256) void cvt_t(const float* __restrict__ src,
                                             short* __restrict__ dst, int K,
                                             int N) {
  __shared__ float tile[32][33];
  const int k0 = blockIdx.y * 32, n0 = blockIdx.x * 32;
  const int tr = threadIdx.x >> 5, tc = threadIdx.x & 31;
#pragma unroll
  for (int i = 0; i < 32; i += 8)
    tile[tr + i][tc] = src[(size_t)(k0 + tr + i) * N + n0 + tc];
  __syncthreads();
#pragma unroll
  for (int i = 0; i < 32; i += 8)
    dst[(size_t)(n0 + tr + i) * K + k0 + tc] = f2bf(tile[tc][tr + i]);
}

// batched 256x256 weight converts: z=0..2 transpose Ww1/Ww2/Wp1, z=3 copy Wp1
__global__ __launch_bounds__(256) void cvt4(const float* __restrict__ Ww1,
                                            const float* __restrict__ Ww2,
                                            const float* __restrict__ Wp1,
                                            short* __restrict__ d0,
                                            short* __restrict__ d1,
                                            short* __restrict__ d2,
                                            short* __restrict__ d3) {
  __shared__ float tile[32][33];
  const int z = blockIdx.z;
  const int k0 = blockIdx.y * 32, n0 = blockIdx.x * 32;
  const int tr = threadIdx.x >> 5, tc = threadIdx.x & 31;
  if (z == 3) {
#pragma unroll
    for (int i = 0; i < 32; i += 8) {
      const size_t o = (size_t)(k0 + tr + i) * 256 + n0 + tc;
      d3[o] = f2bf(Wp1[o]);
    }
    return;
  }
  const float* src = (z == 0) ? Ww1 : (z == 1) ? Ww2 : Wp1;
  short* dst = (z == 0) ? d0 : (z == 1) ? d1 : d2;
#pragma unroll
  for (int i = 0; i < 32; i += 8)
    tile[tr + i][tc] = src[(size_t)(k0 + tr + i) * 256 + n0 + tc];
  __syncthreads();
#pragma unroll
  for (int i = 0; i < 32; i += 8)
    dst[(size_t)(n0 + tr + i) * 256 + k0 + tc] = f2bf(tile[tc][tr + i]);
}

// ---------------- bf16 TN GEMMs, global_load_lds staging ----------------

enum { EPI_TANH = 0, EPI_F32 = 1, EPI_ENC2 = 2 };

// 128x128 tile, BK=64 (two 32-k chunks per barrier window)
template <int EPI>
__global__ __launch_bounds__(256) void gemm128(
    const short* __restrict__ A, const short* __restrict__ Bt,
    const float* __restrict__ bias, float* __restrict__ Cf,
    short* __restrict__ Cb, int M, int N, int K) {
  __shared__ __align__(16) short As[2 * 128 * 32];
  __shared__ __align__(16) short Bs[2 * 128 * 32];
  const int tid = threadIdx.x;
  const int w = tid >> 6, lane = tid & 63, q = lane >> 4, l15 = lane & 15;
  const int wm = (w >> 1) * 64, wn = (w & 1) * 64;
  const int m0 = blockIdx.y * 128, n0 = blockIdx.x * 128;
  const f32x4 fzero = {0.0f, 0.0f, 0.0f, 0.0f};
  f32x4 acc[4][4];
#pragma unroll
  for (int mt = 0; mt < 4; ++mt)
#pragma unroll
    for (int nt = 0; nt < 4; ++nt) acc[mt][nt] = fzero;

  for (int k0 = 0; k0 < K; k0 += 64) {
#pragma unroll
    for (int kcb = 0; kcb < 2; ++kcb)
#pragma unroll
      for (int j = 0; j < 2; ++j) {
        const int c = w * 128 + j * 64 + lane;
        async16(A + (size_t)(m0 + (c >> 2)) * K + k0 + kcb * 32 + (c & 3) * 8,
                &As[kcb * 4096 + (w * 128 + j * 64) * 8]);
        async16(Bt + (size_t)(n0 + (c >> 2)) * K + k0 + kcb * 32 + (c & 3) * 8,
                &Bs[kcb * 4096 + (w * 128 + j * 64) * 8]);
      }
    __syncthreads();
#pragma unroll
    for (int kcb = 0; kcb < 2; ++kcb) {
      bf8 af[4], bfr[4];
#pragma unroll
      for (int mt = 0; mt < 4; ++mt)
        af[mt] =
            *(const bf8*)&As[kcb * 4096 + (wm + mt * 16 + l15) * 32 + q * 8];
#pragma unroll
      for (int nt = 0; nt < 4; ++nt)
        bfr[nt] =
            *(const bf8*)&Bs[kcb * 4096 + (wn + nt * 16 + l15) * 32 + q * 8];
#pragma unroll
      for (int mt = 0; mt < 4; ++mt)
#pragma unroll
        for (int nt = 0; nt < 4; ++nt)
          acc[mt][nt] = __builtin_amdgcn_mfma_f32_16x16x32_bf16(
              af[mt], bfr[nt], acc[mt][nt], 0, 0, 0);
    }
    __syncthreads();
  }
#pragma unroll
  for (int mt = 0; mt < 4; ++mt)
#pragma unroll
    for (int nt = 0; nt < 4; ++nt) {
      const int col = n0 + wn + nt * 16 + l15;
      const float bcol = bias[col];
#pragma unroll
      for (int rg = 0; rg < 4; ++rg) {
        const int row = m0 + wm + mt * 16 + q * 4 + rg;
        const float val = acc[mt][nt][rg] + bcol;
        if constexpr (EPI == EPI_TANH) {
          Cb[(size_t)row * N + col] = f2bf(fast_tanh(val));
        } else {
          Cf[(size_t)row * N + col] = val;
        }
      }
    }
}

template <int EPI>
__global__ __launch_bounds__(256) void gemm64(
    const short* __restrict__ A, const short* __restrict__ Bt,
    const float* __restrict__ bias, float* __restrict__ Cf,
    short* __restrict__ Cb, float* __restrict__ Cf2, int M, int N, int K) {
  __shared__ __align__(16) short As[64 * 32];
  __shared__ __align__(16) short Bs[64 * 32];
  const int tid = threadIdx.x;
  const int w = tid >> 6, lane = tid & 63, q = lane >> 4, l15 = lane & 15;
  const int wm = (w >> 1) * 32, wn = (w & 1) * 32;
  const int m0 = blockIdx.y * 64, n0 = blockIdx.x * 64;
  const f32x4 fzero = {0.0f, 0.0f, 0.0f, 0.0f};
  f32x4 acc[2][2];
#pragma unroll
  for (int mt = 0; mt < 2; ++mt)
#pragma unroll
    for (int nt = 0; nt < 2; ++nt) acc[mt][nt] = fzero;

  for (int k0 = 0; k0 < K; k0 += 32) {
    const int c = w * 64 + lane;
    async16(A + (size_t)(m0 + (c >> 2)) * K + k0 + (c & 3) * 8,
            &As[(w * 64) * 8]);
    async16(Bt + (size_t)(n0 + (c >> 2)) * K + k0 + (c & 3) * 8,
            &Bs[(w * 64) * 8]);
    __syncthreads();
    bf8 af[2], bfr[2];
#pragma unroll
    for (int mt = 0; mt < 2; ++mt)
      af[mt] = *(const bf8*)&As[(wm + mt * 16 + l15) * 32 + q * 8];
#pragma unroll
    for (int nt = 0; nt < 2; ++nt)
      bfr[nt] = *(const bf8*)&Bs[(wn + nt * 16 + l15) * 32 + q * 8];
#pragma unroll
    for (int mt = 0; mt < 2; ++mt)
#pragma unroll
      for (int nt = 0; nt < 2; ++nt)
        acc[mt][nt] = __builtin_amdgcn_mfma_f32_16x16x32_bf16(
            af[mt], bfr[nt], acc[mt][nt], 0, 0, 0);
    __syncthreads();
  }
#pragma unroll
  for (int mt = 0; mt < 2; ++mt)
#pragma unroll
    for (int nt = 0; nt < 2; ++nt) {
      const int col = n0 + wn + nt * 16 + l15;
      const float bcol = bias[col];
#pragma unroll
      for (int rg = 0; rg < 4; ++rg) {
        const int row = m0 + wm + mt * 16 + q * 4 + rg;
        const float val = acc[mt][nt][rg] + bcol;
        if constexpr (EPI == EPI_TANH) {
          Cb[(size_t)row * N + col] = f2bf(fast_tanh(val));
        } else if constexpr (EPI == EPI_F32) {
          Cf[(size_t)row * N + col] = val;
        } else {  // EPI_ENC2: rows<4096 -> z_s (f32+bf16); rows>=4096 -> z_e
          if (row < 4096) {
            Cf[(size_t)row * N + col] = val;
            Cb[(size_t)row * N + col] = f2bf(val);
          } else {
            Cf2[(size_t)(row - 4096) * N + col] = val;
          }
        }
      }
    }
}

// ---------------- W_start fallback ----------------

__global__ __launch_bounds__(256) void init_fb(float* __restrict__ V,
                                               const float* __restrict__ nr) {
  const int row = blockIdx.x * 4 + (threadIdx.x >> 6);
  const int lane = threadIdx.x & 63;
  const size_t off = (size_t)row * 256 + (lane << 2);
  float4 wv = *(const float4*)(V + off);
  float s = wv.x * wv.x + wv.y * wv.y + wv.z * wv.z + wv.w * wv.w;
  s = wave_sum(s);
  const float wn = sqrtf(s + 1e-24f);
  if (wn < 1e-5f) {  // wave-uniform branch
    const float4 n4 = *(const float4*)(nr + off);
    float ns = n4.x * n4.x + n4.y * n4.y + n4.z * n4.z + n4.w * n4.w;
    ns = wave_sum(ns);
    const float nn = sqrtf(ns + 1e-24f);
    const float sc = 1e-4f / (nn + 1e-12f);
    wv.x += sc * n4.x; wv.y += sc * n4.y; wv.z += sc * n4.z; wv.w += sc * n4.w;
    *(float4*)(V + off) = wv;
  }
}

// ---------------- fused trace ----------------
// 256 blocks x 1024 threads (16 waves = 4 waves/SIMD from one block/CU).
// Wave w owns cols w*16 + l15 (one 16-col tile). Thread owns rows q*4+rg
// (MFMA C-native). Activation LDS XOR-swizzled: elem (m,k) at chunk
// kc*16+(m^(kc&15)), kc=k>>3 -> b128 reads lane*16B, u16 writes 2-way max.
// Row-sums: DPP row_ror butterfly -> l15==0 LDS atomicAdd into ping-pong
// buffers (parity st&1, zeroed 2 stages ahead) -> broadcast float4 read.

__global__ __launch_bounds__(1024, 4) void trace_fused(
    const float* __restrict__ Xg, const float* __restrict__ Vg,
    const float* __restrict__ ZEg, const short* __restrict__ WT,
    const short* __restrict__ Wp1b, const float* __restrict__ bp1,
    const float* __restrict__ wp2, float* __restrict__ out) {
  constexpr float hs = H_STEP;
  __shared__ __align__(16) short XsL[4096];
  __shared__ __align__(16) short UL[4096];
  __shared__ __align__(16) float gvb[2][16];
  __shared__ __align__(16) float vvb[2][16];
  __shared__ __align__(16) float db[2][16];
  const int tid = threadIdx.x;
  const int w = tid >> 6, lane = tid & 63, q = lane >> 4, l15 = lane & 15;
  const int r0 = blockIdx.x * 16, rb = q * 4;

  if (tid < 16) {
    gvb[0][tid] = 0.0f; gvb[1][tid] = 0.0f;
    vvb[0][tid] = 0.0f; vvb[1][tid] = 0.0f;
    db[0][tid] = 0.0f;  db[1][tid] = 0.0f;
  }

  const int c = w * 16 + l15;  // this thread's column
  bf8 B1f[8], B2f[8];
#pragma unroll
  for (int ks = 0; ks < 8; ++ks) {
    B1f[ks] = *(const bf8*)(WT + c * 256 + ks * 32 + q * 8);    // Wp1^T rows
    B2f[ks] = *(const bf8*)(Wp1b + c * 256 + ks * 32 + q * 8);  // Wp1 rows
  }
  const float bp1c = bp1[c];
  const float wp2c = wp2[c];
  int wadr[4], radr[8];
  {
    const int kc = c >> 3, cx = kc & 15, cl = c & 7;
#pragma unroll
    for (int rg = 0; rg < 4; ++rg)
      wadr[rg] = kc * 128 + ((rb + rg) ^ cx) * 8 + cl;
#pragma unroll
    for (int ks = 0; ks < 8; ++ks) {
      const int kq = ks * 4 + q;
      radr[ks] = (kq * 16 + (l15 ^ (kq & 15))) * 8;
    }
  }
  float x[4], v[4], ap[4], xacc[4], vacc[4], ze[4], md[4];
#pragma unroll
  for (int rg = 0; rg < 4; ++rg) {
    const size_t off = (size_t)(r0 + rb + rg) * 256 + c;
    x[rg] = Xg[off];
    v[rg] = Vg[off];
    ze[rg] = ZEg[off];
    ap[rg] = 0.0f;
    xacc[rg] = 0.0f;
    vacc[rg] = 0.0f;
    md[rg] = 3.4e38f;
  }
  const f32x4 fzero = {0.0f, 0.0f, 0.0f, 0.0f};
  const float cxv_t[4] = {0.0f, 0.5f * hs, 0.5f * hs, hs};
  const float cxa_t[4] = {0.0f, 0.0f, 0.25f * hs * hs, 0.5f * hs * hs};
  const float cva_t[4] = {0.0f, 0.5f * hs, 0.5f * hs, hs};

#pragma unroll 1
  for (int step = 0; step < 15; ++step) {
#pragma unroll
    for (int st = 0; st < 4; ++st) {
      const int p = st & 1;
      const float cxv = cxv_t[st], cxa = cxa_t[st], cva = cva_t[st];
      // 1. stage position -> LDS
#pragma unroll
      for (int rg = 0; rg < 4; ++rg)
        XsL[wadr[rg]] = f2bf(x[rg] + cxv * v[rg] + cxa * ap[rg]);
      __syncthreads();
      // 2. matmul1: H[:,c] = Xs @ Wp1
      f32x4 acc;
      {
        f32x4 a0 = fzero, a1 = fzero;
#pragma unroll
        for (int ks = 0; ks < 8; ks += 2) {
          const bf8 f0 = *(const bf8*)&XsL[radr[ks]];
          const bf8 f1 = *(const bf8*)&XsL[radr[ks + 1]];
          a0 = __builtin_amdgcn_mfma_f32_16x16x32_bf16(f0, B1f[ks], a0, 0, 0,
                                                       0);
          a1 = __builtin_amdgcn_mfma_f32_16x16x32_bf16(f1, B1f[ks + 1], a1, 0,
                                                       0, 0);
        }
        acc = a0 + a1;
      }
      // epilogue1: U = sech^2(s) * wp2 -> LDS; zero next stage's sum buffers
#pragma unroll
      for (int rg = 0; rg < 4; ++rg)
        UL[wadr[rg]] = f2bf(sech2(acc[rg] + bp1c) * wp2c);
      if (tid < 16) {
        gvb[p ^ 1][tid] = 0.0f;
        vvb[p ^ 1][tid] = 0.0f;
      }
      __syncthreads();
      // 3. matmul2: G[:,c] = U @ Wp1^T
      {
        f32x4 a0 = fzero, a1 = fzero;
#pragma unroll
        for (int ks = 0; ks < 8; ks += 2) {
          const bf8 f0 = *(const bf8*)&UL[radr[ks]];
          const bf8 f1 = *(const bf8*)&UL[radr[ks + 1]];
          a0 = __builtin_amdgcn_mfma_f32_16x16x32_bf16(f0, B2f[ks], a0, 0, 0,
                                                       0);
          a1 = __builtin_amdgcn_mfma_f32_16x16x32_bf16(f1, B2f[ks + 1], a1, 0,
                                                       0, 0);
        }
        acc = a0 + a1;
      }
      // row partials over this wave's 16 cols, DPP-reduce, LDS atomics
      float pg[4], pv[4];
#pragma unroll
      for (int rg = 0; rg < 4; ++rg) {
        const float vs = fmaf(cva, ap[rg], v[rg]);
        pg[rg] = red16(acc[rg] * vs);
        pv[rg] = red16(vs * vs);
      }
      if (l15 == 0) {
#pragma unroll
        for (int rg = 0; rg < 4; ++rg) {
          atomicAdd(&gvb[p][rb + rg], pg[rg]);
          atomicAdd(&vvb[p][rb + rg], pv[rg]);
        }
      }
      __syncthreads();
      // 4. broadcast read + accel + RK4 accumulation
      const f32x4 gv4 = *(const f32x4*)&gvb[p][rb];
      const f32x4 vv4 = *(const f32x4*)&vvb[p][rb];
#pragma unroll
      for (int rg = 0; rg < 4; ++rg) {
        const float vs = fmaf(cva, ap[rg], v[rg]);
        const float a = -gv4[rg] * vs + 0.5f * vv4[rg] * acc[rg];
        ap[rg] = a;
        if (st == 0) {
          xacc[rg] = a;
          vacc[rg] = a;
        } else if (st < 3) {
          xacc[rg] += a;
          vacc[rg] += 2.0f * a;
        } else {
          vacc[rg] += a;
        }
      }
      // 5. step update + closest approach
      if (st == 3) {
        const int sp = step & 1;
        float pd[4];
#pragma unroll
        for (int rg = 0; rg < 4; ++rg) {
          const float xn = x[rg] + hs * v[rg] + (hs * hs / 6.0f) * xacc[rg];
          const float vn = v[rg] + (hs / 6.0f) * vacc[rg];
          x[rg] = xn;
          v[rg] = vn;
          const float d = xn - ze[rg];
          pd[rg] = red16(d * d);
        }
        if (l15 == 0) {
#pragma unroll
          for (int rg = 0; rg < 4; ++rg) atomicAdd(&db[sp][rb + rg], pd[rg]);
        }
        if (tid < 16) db[sp ^ 1][tid] = 0.0f;
        __syncthreads();
        const f32x4 d4 = *(const f32x4*)&db[sp][rb];
#pragma unroll
        for (int rg = 0; rg < 4; ++rg) md[rg] = fminf(md[rg], d4[rg]);
      }
    }
  }
  if (w == 0 && l15 == 0)  // q=0..3 cover rows 0..15 (md broadcast-replicated)
    atomicAdd(out, (md[0] + md[1] + md[2] + md[3]) * (1.0f / 4096.0f));
}

}  // namespace

extern "C" void kernel_launch(void* const* d_in, const int* in_sizes, int n_in,
                              void* d_out, int out_size, void* d_ws,
                              size_t ws_size, hipStream_t stream) {
  (void)in_sizes; (void)n_in; (void)out_size; (void)ws_size;
  const float* x_start = (const float*)d_in[0];
  const float* x_end = (const float*)d_in[1];
  const float* noise = (const float*)d_in[2];
  const float* W1 = (const float*)d_in[3];
  const float* b1 = (const float*)d_in[4];
  const float* W2 = (const float*)d_in[5];
  const float* b2 = (const float*)d_in[6];
  const float* Ww1 = (const float*)d_in[7];
  const float* bw1 = (const float*)d_in[8];
  const float* Ww2 = (const float*)d_in[9];
  const float* bw2 = (const float*)d_in[10];
  const float* Wp1 = (const float*)d_in[11];
  const float* bp1 = (const float*)d_in[12];
  const float* wp2 = (const float*)d_in[13];
  float* out = (float*)d_out;

  // workspace layout (~66 MB)
  float* Xf = (float*)d_ws;                        // z_s      4096*256 f32
  float* ZEf = Xf + (size_t)4096 * 256;            // z_e
  float* Vf = ZEf + (size_t)4096 * 256;            // W_start
  short* Xb = (short*)(Vf + (size_t)4096 * 256);   // z_s bf16 4096*256
  short* HWb = Xb + (size_t)4096 * 256;            // wind hidden bf16
  short* XSb = HWb + (size_t)4096 * 256;           // x bf16   8192*2048
  short* H1b = XSb + (size_t)8192 * 2048;          // enc hidden bf16 8192*1024
  short* W1T = H1b + (size_t)8192 * 1024;          // 1024*2048
  short* W2T = W1T + (size_t)1024 * 2048;          // 256*1024
  short* Ww1T = W2T + (size_t)256 * 1024;
  short* Ww2T = Ww1T + 65536;
  short* WpT = Ww2T + 65536;                       // Wp1^T
  short* Wp1b = WpT + 65536;                       // Wp1 row-major

  const dim3 blk(256);

  cvt_t<<<dim3(32, 64), blk, 0, stream>>>(W1, W1T, 2048, 1024);
  cvt_t<<<dim3(8, 32), blk, 0, stream>>>(W2, W2T, 1024, 256);
  cvt4<<<dim3(8, 8, 4), blk, 0, stream>>>(Ww1, Ww2, Wp1, Ww1T, Ww2T, WpT,
                                          Wp1b);
  // fused z_s/z_e encoder: rows 0-4095 = x_start, 4096-8191 = x_end
  cvt2<<<2048, blk, 0, stream>>>(x_start, x_end, XSb, (long)8192 * 2048);
  gemm128<EPI_TANH><<<dim3(8, 64), blk, 0, stream>>>(
      XSb, W1T, b1, nullptr, H1b, 8192, 1024, 2048);
  gemm64<EPI_ENC2><<<dim3(4, 128), blk, 0, stream>>>(
      H1b, W2T, b2, Xf, Xb, ZEf, 8192, 256, 1024);
  // W_start = wind(z_s)
  gemm64<EPI_TANH><<<dim3(4, 64), blk, 0, stream>>>(
      Xb, Ww1T, bw1, nullptr, HWb, nullptr, 4096, 256, 256);
  gemm64<EPI_F32><<<dim3(4, 64), blk, 0, stream>>>(
      HWb, Ww2T, bw2, Vf, nullptr, nullptr, 4096, 256, 256);
  init_fb<<<1024, blk, 0, stream>>>(Vf, noise);

  hipMemsetAsync(d_out, 0, sizeof(float), stream);
  trace_fused<<<256, dim3(1024), 0, stream>>>(Xf, Vf, ZEf, WpT, Wp1b, bp1,
                                              wp2, out);
}

// Round 6
// 325.536 us; speedup vs baseline: 1.1729x; 1.1729x over previous
//
// Round 6: R4 trace shape (512thr, lb(512,2)) + wind MLP & fallback fused into
// trace prologue (register-lifetime-disjoint weight frags); wp2 folded into
// the bf16 Wp1 copy; all weight converts in one flat kernel. 6 dispatches.

#include <hip/hip_runtime.h>
#include <math.h>

typedef short bf8 __attribute__((ext_vector_type(8)));   // 8 bf16 = 4 VGPR
typedef float f32x4 __attribute__((ext_vector_type(4))); // MFMA acc

namespace {

constexpr float H_STEP = 1.0f / 15.0f;

__device__ inline short f2bf(float f) {  // RNE f32 -> bf16
  unsigned u = __float_as_uint(f);
  u += 0x7fffu + ((u >> 16) & 1u);
  return (short)(u >> 16);
}

__device__ inline float fast_tanh(float x) {
  const float ax = fabsf(x);
  const float e = __expf(-2.0f * ax);
  const float t = (1.0f - e) * __builtin_amdgcn_rcpf(1.0f + e);
  return copysignf(t, x);
}

// 1 - tanh(x)^2 = 4 e / (1+e)^2, e = exp(-2|x|)
__device__ inline float sech2(float x) {
  const float e = __expf(-2.0f * fabsf(x));
  const float r = __builtin_amdgcn_rcpf(1.0f + e);
  return 4.0f * e * r * r;
}

__device__ inline float wave_sum(float v) {
#pragma unroll
  for (int sh = 32; sh > 0; sh >>= 1) v += __shfl_xor(v, sh);
  return v;
}

// sum over each 16-lane group via DPP row_ror 1/2/4/8 (VALU-rate butterfly)
template <int CTRL>
__device__ inline float dppadd(float v) {
  return v + __int_as_float(__builtin_amdgcn_update_dpp(
                 0, __float_as_int(v), CTRL, 0xF, 0xF, true));
}
__device__ inline float red16(float v) {
  v = dppadd<0x121>(v);
  v = dppadd<0x122>(v);
  v = dppadd<0x124>(v);
  v = dppadd<0x128>(v);
  return v;
}

// async global->LDS, 16B per lane. LDS dest = wave-uniform base + lane*16.
__device__ inline void async16(const void* g, void* l) {
  __builtin_amdgcn_global_load_lds((__attribute__((address_space(1))) void*)g,
                                   (__attribute__((address_space(3))) void*)l,
                                   16, 0, 0);
}

// ---------------- converts ----------------

// both encoder inputs -> one bf16 buffer [8192][2048]
__global__ __launch_bounds__(256) void cvt2(const float* __restrict__ a,
                                            const float* __restrict__ b,
                                            short* __restrict__ dst, long n) {
  const long half = n >> 1;
  long i = ((long)blockIdx.x * 256 + threadIdx.x) * 4;
  const long stride = (long)gridDim.x * 1024;
  for (; i < n; i += stride) {
    const float* s = (i < half) ? (a + i) : (b + (i - half));
    const float4 f = *(const float4*)s;
    ushort4 o;
    o.x = (unsigned short)f2bf(f.x);
    o.y = (unsigned short)f2bf(f.y);
    o.z = (unsigned short)f2bf(f.z);
    o.w = (unsigned short)f2bf(f.w);
    *(ushort4*)(dst + i) = o;
  }
}

// all weight converts, flat block-id decode:
// [0,2048): W1^T (2048x1024 -> 1024x2048), [2048,2304): W2^T (1024x256),
// [2304,2368): Ww1^T, [2368,2432): Ww2^T, [2432,2496): Wp1^T,
// [2496,2560): Wp1 row-major copy scaled by wp2[col].
__global__ __launch_bounds__(256) void cvt_w(
    const float* __restrict__ W1, const float* __restrict__ W2,
    const float* __restrict__ Ww1, const float* __restrict__ Ww2,
    const float* __restrict__ Wp1, const float* __restrict__ wp2,
    short* __restrict__ W1T, short* __restrict__ W2T,
    short* __restrict__ Ww1T, short* __restrict__ Ww2T,
    short* __restrict__ WpT, short* __restrict__ Wp1s) {
  __shared__ float tile[32][33];
  const int id = blockIdx.x;
  const int tr = threadIdx.x >> 5, tc = threadIdx.x & 31;
  const float* src;
  short* dst;
  int K, N, kt, nt;
  if (id < 2048) {
    src = W1; dst = W1T; K = 2048; N = 1024; kt = id >> 5; nt = id & 31;
  } else if (id < 2304) {
    src = W2; dst = W2T; K = 1024; N = 256; kt = (id - 2048) >> 3; nt = (id - 2048) & 7;
  } else if (id < 2368) {
    src = Ww1; dst = Ww1T; K = 256; N = 256; kt = (id - 2304) >> 3; nt = (id - 2304) & 7;
  } else if (id < 2432) {
    src = Ww2; dst = Ww2T; K = 256; N = 256; kt = (id - 2368) >> 3; nt = (id - 2368) & 7;
  } else if (id < 2496) {
    src = Wp1; dst = WpT; K = 256; N = 256; kt = (id - 2432) >> 3; nt = (id - 2432) & 7;
  } else {  // scaled copy
    const int lid = id - 2496;
    const int k0 = (lid >> 3) * 32, n0 = (lid & 7) * 32;
#pragma unroll
    for (int i = 0; i < 32; i += 8) {
      const size_t o = (size_t)(k0 + tr + i) * 256 + n0 + tc;
      Wp1s[o] = f2bf(Wp1[o] * wp2[n0 + tc]);
    }
    return;
  }
  const int k0 = kt * 32, n0 = nt * 32;
#pragma unroll
  for (int i = 0; i < 32; i += 8)
    tile[tr + i][tc] = src[(size_t)(k0 + tr + i) * N + n0 + tc];
  __syncthreads();
#pragma unroll
  for (int i = 0; i < 32; i += 8)
    dst[(size_t)(n0 + tr + i) * K + k0 + tc] = f2bf(tile[tc][tr + i]);
}

// ---------------- bf16 TN GEMMs, global_load_lds staging ----------------

// 128x128 tile, BK=64, tanh->bf16 epilogue (encoder L1)
__global__ __launch_bounds__(256) void gemm128_tanh(
    const short* __restrict__ A, const short* __restrict__ Bt,
    const float* __restrict__ bias, short* __restrict__ Cb, int M, int N,
    int K) {
  __shared__ __align__(16) short As[2 * 128 * 32];
  __shared__ __align__(16) short Bs[2 * 128 * 32];
  const int tid = threadIdx.x;
  const int w = tid >> 6, lane = tid & 63, q = lane >> 4, l15 = lane & 15;
  const int wm = (w >> 1) * 64, wn = (w & 1) * 64;
  const int m0 = blockIdx.y * 128, n0 = blockIdx.x * 128;
  const f32x4 fzero = {0.0f, 0.0f, 0.0f, 0.0f};
  f32x4 acc[4][4];
#pragma unroll
  for (int mt = 0; mt < 4; ++mt)
#pragma unroll
    for (int nt = 0; nt < 4; ++nt) acc[mt][nt] = fzero;

  for (int k0 = 0; k0 < K; k0 += 64) {
#pragma unroll
    for (int kcb = 0; kcb < 2; ++kcb)
#pragma unroll
      for (int j = 0; j < 2; ++j) {
        const int c = w * 128 + j * 64 + lane;
        async16(A + (size_t)(m0 + (c >> 2)) * K + k0 + kcb * 32 + (c & 3) * 8,
                &As[kcb * 4096 + (w * 128 + j * 64) * 8]);
        async16(Bt + (size_t)(n0 + (c >> 2)) * K + k0 + kcb * 32 + (c & 3) * 8,
                &Bs[kcb * 4096 + (w * 128 + j * 64) * 8]);
      }
    __syncthreads();
#pragma unroll
    for (int kcb = 0; kcb < 2; ++kcb) {
      bf8 af[4], bfr[4];
#pragma unroll
      for (int mt = 0; mt < 4; ++mt)
        af[mt] =
            *(const bf8*)&As[kcb * 4096 + (wm + mt * 16 + l15) * 32 + q * 8];
#pragma unroll
      for (int nt = 0; nt < 4; ++nt)
        bfr[nt] =
            *(const bf8*)&Bs[kcb * 4096 + (wn + nt * 16 + l15) * 32 + q * 8];
#pragma unroll
      for (int mt = 0; mt < 4; ++mt)
#pragma unroll
        for (int nt = 0; nt < 4; ++nt)
          acc[mt][nt] = __builtin_amdgcn_mfma_f32_16x16x32_bf16(
              af[mt], bfr[nt], acc[mt][nt], 0, 0, 0);
    }
    __syncthreads();
  }
#pragma unroll
  for (int mt = 0; mt < 4; ++mt)
#pragma unroll
    for (int nt = 0; nt < 4; ++nt) {
      const int col = n0 + wn + nt * 16 + l15;
      const float bcol = bias[col];
#pragma unroll
      for (int rg = 0; rg < 4; ++rg) {
        const int row = m0 + wm + mt * 16 + q * 4 + rg;
        Cb[(size_t)row * N + col] = f2bf(fast_tanh(acc[mt][nt][rg] + bcol));
      }
    }
}

// 64x64 tile encoder L2: rows<4096 -> z_s (f32), rows>=4096 -> z_e (f32)
__global__ __launch_bounds__(256) void gemm64_enc2(
    const short* __restrict__ A, const short* __restrict__ Bt,
    const float* __restrict__ bias, float* __restrict__ Zs,
    float* __restrict__ Ze, int M, int N, int K) {
  __shared__ __align__(16) short As[64 * 32];
  __shared__ __align__(16) short Bs[64 * 32];
  const int tid = threadIdx.x;
  const int w = tid >> 6, lane = tid & 63, q = lane >> 4, l15 = lane & 15;
  const int wm = (w >> 1) * 32, wn = (w & 1) * 32;
  const int m0 = blockIdx.y * 64, n0 = blockIdx.x * 64;
  const f32x4 fzero = {0.0f, 0.0f, 0.0f, 0.0f};
  f32x4 acc[2][2];
#pragma unroll
  for (int mt = 0; mt < 2; ++mt)
#pragma unroll
    for (int nt = 0; nt < 2; ++nt) acc[mt][nt] = fzero;

  for (int k0 = 0; k0 < K; k0 += 32) {
    const int c = w * 64 + lane;
    async16(A + (size_t)(m0 + (c >> 2)) * K + k0 + (c & 3) * 8,
            &As[(w * 64) * 8]);
    async16(Bt + (size_t)(n0 + (c >> 2)) * K + k0 + (c & 3) * 8,
            &Bs[(w * 64) * 8]);
    __syncthreads();
    bf8 af[2], bfr[2];
#pragma unroll
    for (int mt = 0; mt < 2; ++mt)
      af[mt] = *(const bf8*)&As[(wm + mt * 16 + l15) * 32 + q * 8];
#pragma unroll
    for (int nt = 0; nt < 2; ++nt)
      bfr[nt] = *(const bf8*)&Bs[(wn + nt * 16 + l15) * 32 + q * 8];
#pragma unroll
    for (int mt = 0; mt < 2; ++mt)
#pragma unroll
      for (int nt = 0; nt < 2; ++nt)
        acc[mt][nt] = __builtin_amdgcn_mfma_f32_16x16x32_bf16(
            af[mt], bfr[nt], acc[mt][nt], 0, 0, 0);
    __syncthreads();
  }
#pragma unroll
  for (int mt = 0; mt < 2; ++mt)
#pragma unroll
    for (int nt = 0; nt < 2; ++nt) {
      const int col = n0 + wn + nt * 16 + l15;
      const float bcol = bias[col];
#pragma unroll
      for (int rg = 0; rg < 4; ++rg) {
        const int row = m0 + wm + mt * 16 + q * 4 + rg;
        const float val = acc[mt][nt][rg] + bcol;
        if (row < 4096)
          Zs[(size_t)row * N + col] = val;
        else
          Ze[(size_t)(row - 4096) * N + col] = val;
      }
    }
}

// ---------------- fused wind + fallback + trace ----------------
// 256 blocks x 512 threads (8 waves, 2/SIMD, lb(512,2) -> 256 reg budget).
// Wave w owns cols w*32 + t*16 + l15 (t in {0,1}); thread owns rows q*4+rg.
// Prologue: wind MLP (Ww1^T/Ww2^T frags, disjoint lifetime from Wp frags),
// degenerate-wind fallback (row-norm reductions via DPP+LDS atomics).
// Main loop: R4 structure. Activation LDS XOR-swizzled (0 bank conflicts).
// Wp1s = Wp1 pre-scaled by wp2 (G-matmul absorbs the (1-h^2)*wp2 scale).

__global__ __launch_bounds__(512, 2) void trace_fused(
    const float* __restrict__ Xg, const float* __restrict__ ZEg,
    const float* __restrict__ NZg, const short* __restrict__ WT,
    const short* __restrict__ Wp1s, const short* __restrict__ Ww1T,
    const short* __restrict__ Ww2T, const float* __restrict__ bw1,
    const float* __restrict__ bw2, const float* __restrict__ bp1,
    float* __restrict__ out) {
  constexpr float hs = H_STEP;
  __shared__ __align__(16) short XsL[4096];
  __shared__ __align__(16) short UL[4096];
  __shared__ __align__(16) float gvb[2][16];
  __shared__ __align__(16) float vvb[2][16];
  __shared__ __align__(16) float db[2][16];
  const int tid = threadIdx.x;
  const int w = tid >> 6, lane = tid & 63, q = lane >> 4, l15 = lane & 15;
  const int r0 = blockIdx.x * 16, rb = q * 4;

  if (tid < 16) {
    gvb[0][tid] = 0.0f; gvb[1][tid] = 0.0f;
    vvb[0][tid] = 0.0f; vvb[1][tid] = 0.0f;
    db[0][tid] = 0.0f;  db[1][tid] = 0.0f;
  }

  int cc[2], wadr[2][4], radr[8];
  float bp1c[2], bw1c[2], bw2c[2];
#pragma unroll
  for (int t = 0; t < 2; ++t) {
    const int c = w * 32 + t * 16 + l15;
    cc[t] = c;
    const int kc = c >> 3, cx = kc & 15, cl = c & 7;
#pragma unroll
    for (int rg = 0; rg < 4; ++rg)
      wadr[t][rg] = kc * 128 + ((rb + rg) ^ cx) * 8 + cl;
    bp1c[t] = bp1[c];
    bw1c[t] = bw1[c];
    bw2c[t] = bw2[c];
  }
#pragma unroll
  for (int ks = 0; ks < 8; ++ks) {
    const int kq = ks * 4 + q;
    radr[ks] = (kq * 16 + (l15 ^ (kq & 15))) * 8;
  }
  float x[2][4], ze[2][4], nz[2][4];
#pragma unroll
  for (int t = 0; t < 2; ++t)
#pragma unroll
    for (int rg = 0; rg < 4; ++rg) {
      const size_t off = (size_t)(r0 + rb + rg) * 256 + cc[t];
      x[t][rg] = Xg[off];
      ze[t][rg] = ZEg[off];
      nz[t][rg] = NZg[off];
    }
  const f32x4 fzero = {0.0f, 0.0f, 0.0f, 0.0f};

  // ---- wind MLP ----
  float v[2][4];
  {
    bf8 Wf1[2][8], Wf2[2][8];
#pragma unroll
    for (int t = 0; t < 2; ++t)
#pragma unroll
      for (int ks = 0; ks < 8; ++ks) {
        Wf1[t][ks] = *(const bf8*)(Ww1T + cc[t] * 256 + ks * 32 + q * 8);
        Wf2[t][ks] = *(const bf8*)(Ww2T + cc[t] * 256 + ks * 32 + q * 8);
      }
#pragma unroll
    for (int t = 0; t < 2; ++t)
#pragma unroll
      for (int rg = 0; rg < 4; ++rg) XsL[wadr[t][rg]] = f2bf(x[t][rg]);
    __syncthreads();
    bf8 af[8];
#pragma unroll
    for (int ks = 0; ks < 8; ++ks) af[ks] = *(const bf8*)&XsL[radr[ks]];
    f32x4 acc[2];
#pragma unroll
    for (int t = 0; t < 2; ++t) {
      f32x4 a0 = fzero, a1 = fzero;
#pragma unroll
      for (int ks = 0; ks < 8; ks += 2) {
        a0 = __builtin_amdgcn_mfma_f32_16x16x32_bf16(af[ks], Wf1[t][ks], a0,
                                                     0, 0, 0);
        a1 = __builtin_amdgcn_mfma_f32_16x16x32_bf16(af[ks + 1],
                                                     Wf1[t][ks + 1], a1, 0, 0,
                                                     0);
      }
      acc[t] = a0 + a1;
    }
#pragma unroll
    for (int t = 0; t < 2; ++t)
#pragma unroll
      for (int rg = 0; rg < 4; ++rg)
        UL[wadr[t][rg]] = f2bf(fast_tanh(acc[t][rg] + bw1c[t]));
    __syncthreads();
#pragma unroll
    for (int ks = 0; ks < 8; ++ks) af[ks] = *(const bf8*)&UL[radr[ks]];
#pragma unroll
    for (int t = 0; t < 2; ++t) {
      f32x4 a0 = fzero, a1 = fzero;
#pragma unroll
      for (int ks = 0; ks < 8; ks += 2) {
        a0 = __builtin_amdgcn_mfma_f32_16x16x32_bf16(af[ks], Wf2[t][ks], a0,
                                                     0, 0, 0);
        a1 = __builtin_amdgcn_mfma_f32_16x16x32_bf16(af[ks + 1],
                                                     Wf2[t][ks + 1], a1, 0, 0,
                                                     0);
      }
      acc[t] = a0 + a1;
#pragma unroll
      for (int rg = 0; rg < 4; ++rg) v[t][rg] = acc[t][rg] + bw2c[t];
    }
    // ---- degenerate-wind fallback ----
    float pn[4], pm[4];
#pragma unroll
    for (int rg = 0; rg < 4; ++rg) {
      pn[rg] = red16(v[0][rg] * v[0][rg] + v[1][rg] * v[1][rg]);
      pm[rg] = red16(nz[0][rg] * nz[0][rg] + nz[1][rg] * nz[1][rg]);
    }
    if (l15 == 0) {
#pragma unroll
      for (int rg = 0; rg < 4; ++rg) {
        atomicAdd(&gvb[0][rb + rg], pn[rg]);
        atomicAdd(&vvb[0][rb + rg], pm[rg]);
      }
    }
    __syncthreads();
#pragma unroll
    for (int rg = 0; rg < 4; ++rg) {
      const float wn = sqrtf(gvb[0][rb + rg] + 1e-24f);
      const float sc = (wn < 1e-5f)
                           ? 1e-4f / (sqrtf(vvb[0][rb + rg] + 1e-24f) + 1e-12f)
                           : 0.0f;
      v[0][rg] = fmaf(sc, nz[0][rg], v[0][rg]);
      v[1][rg] = fmaf(sc, nz[1][rg], v[1][rg]);
    }
    __syncthreads();
    if (tid < 16) {
      gvb[0][tid] = 0.0f;
      vvb[0][tid] = 0.0f;
    }
  }

  // ---- trace weight frags (Wf regs dead, reused by allocator) ----
  bf8 B1f[2][8], B2f[2][8];
#pragma unroll
  for (int t = 0; t < 2; ++t)
#pragma unroll
    for (int ks = 0; ks < 8; ++ks) {
      B1f[t][ks] = *(const bf8*)(WT + cc[t] * 256 + ks * 32 + q * 8);
      B2f[t][ks] = *(const bf8*)(Wp1s + cc[t] * 256 + ks * 32 + q * 8);
    }
  float ap[2][4], xacc[2][4], vacc[2][4], md[4];
#pragma unroll
  for (int rg = 0; rg < 4; ++rg) {
    ap[0][rg] = 0.0f; ap[1][rg] = 0.0f;
    xacc[0][rg] = 0.0f; xacc[1][rg] = 0.0f;
    vacc[0][rg] = 0.0f; vacc[1][rg] = 0.0f;
    md[rg] = 3.4e38f;
  }
  const float cxv_t[4] = {0.0f, 0.5f * hs, 0.5f * hs, hs};
  const float cxa_t[4] = {0.0f, 0.0f, 0.25f * hs * hs, 0.5f * hs * hs};
  const float cva_t[4] = {0.0f, 0.5f * hs, 0.5f * hs, hs};

#pragma unroll 1
  for (int step = 0; step < 15; ++step) {
#pragma unroll
    for (int st = 0; st < 4; ++st) {
      const int p = st & 1;
      const float cxv = cxv_t[st], cxa = cxa_t[st], cva = cva_t[st];
      // 1. stage position -> LDS
#pragma unroll
      for (int t = 0; t < 2; ++t)
#pragma unroll
        for (int rg = 0; rg < 4; ++rg)
          XsL[wadr[t][rg]] =
              f2bf(x[t][rg] + cxv * v[t][rg] + cxa * ap[t][rg]);
      __syncthreads();
      // 2. matmul1: H = Xs @ Wp1
      bf8 af[8];
#pragma unroll
      for (int ks = 0; ks < 8; ++ks) af[ks] = *(const bf8*)&XsL[radr[ks]];
      f32x4 acc[2];
#pragma unroll
      for (int t = 0; t < 2; ++t) {
        f32x4 a0 = fzero, a1 = fzero;
#pragma unroll
        for (int ks = 0; ks < 8; ks += 2) {
          a0 = __builtin_amdgcn_mfma_f32_16x16x32_bf16(af[ks], B1f[t][ks], a0,
                                                       0, 0, 0);
          a1 = __builtin_amdgcn_mfma_f32_16x16x32_bf16(af[ks + 1],
                                                       B1f[t][ks + 1], a1, 0,
                                                       0, 0);
        }
        acc[t] = a0 + a1;
      }
      // epilogue1: U = sech^2 (wp2 absorbed into Wp1s) -> LDS
#pragma unroll
      for (int t = 0; t < 2; ++t)
#pragma unroll
        for (int rg = 0; rg < 4; ++rg)
          UL[wadr[t][rg]] = f2bf(sech2(acc[t][rg] + bp1c[t]));
      if (tid < 16) {
        gvb[p ^ 1][tid] = 0.0f;
        vvb[p ^ 1][tid] = 0.0f;
      }
      __syncthreads();
      // 3. matmul2: G = U @ (wp2*Wp1)^T
#pragma unroll
      for (int ks = 0; ks < 8; ++ks) af[ks] = *(const bf8*)&UL[radr[ks]];
#pragma unroll
      for (int t = 0; t < 2; ++t) {
        f32x4 a0 = fzero, a1 = fzero;
#pragma unroll
        for (int ks = 0; ks < 8; ks += 2) {
          a0 = __builtin_amdgcn_mfma_f32_16x16x32_bf16(af[ks], B2f[t][ks], a0,
                                                       0, 0, 0);
          a1 = __builtin_amdgcn_mfma_f32_16x16x32_bf16(af[ks + 1],
                                                       B2f[t][ks + 1], a1, 0,
                                                       0, 0);
        }
        acc[t] = a0 + a1;
      }
      // row reductions
      float vs[2][4], pg[4], pv[4];
#pragma unroll
      for (int rg = 0; rg < 4; ++rg) {
        vs[0][rg] = fmaf(cva, ap[0][rg], v[0][rg]);
        vs[1][rg] = fmaf(cva, ap[1][rg], v[1][rg]);
        pg[rg] = red16(fmaf(acc[0][rg], vs[0][rg], acc[1][rg] * vs[1][rg]));
        pv[rg] = red16(fmaf(vs[0][rg], vs[0][rg], vs[1][rg] * vs[1][rg]));
      }
      if (l15 == 0) {
#pragma unroll
        for (int rg = 0; rg < 4; ++rg) {
          atomicAdd(&gvb[p][rb + rg], pg[rg]);
          atomicAdd(&vvb[p][rb + rg], pv[rg]);
        }
      }
      __syncthreads();
      // 4. broadcast read + accel + RK4 accumulation
      const f32x4 gv4 = *(const f32x4*)&gvb[p][rb];
      const f32x4 vv4 = *(const f32x4*)&vvb[p][rb];
#pragma unroll
      for (int t = 0; t < 2; ++t)
#pragma unroll
        for (int rg = 0; rg < 4; ++rg) {
          const float a = -gv4[rg] * vs[t][rg] + 0.5f * vv4[rg] * acc[t][rg];
          ap[t][rg] = a;
          if (st == 0) {
            xacc[t][rg] = a;
            vacc[t][rg] = a;
          } else if (st < 3) {
            xacc[t][rg] += a;
            vacc[t][rg] += 2.0f * a;
          } else {
            vacc[t][rg] += a;
          }
        }
      // 5. step update + closest approach
      if (st == 3) {
        const int sp = step & 1;
        float pd[4];
#pragma unroll
        for (int rg = 0; rg < 4; ++rg) {
          float acc_d = 0.0f;
#pragma unroll
          for (int t = 0; t < 2; ++t) {
            const float xn =
                x[t][rg] + hs * v[t][rg] + (hs * hs / 6.0f) * xacc[t][rg];
            const float vn = v[t][rg] + (hs / 6.0f) * vacc[t][rg];
            x[t][rg] = xn;
            v[t][rg] = vn;
            const float d = xn - ze[t][rg];
            acc_d = fmaf(d, d, acc_d);
          }
          pd[rg] = red16(acc_d);
        }
        if (l15 == 0) {
#pragma unroll
          for (int rg = 0; rg < 4; ++rg) atomicAdd(&db[sp][rb + rg], pd[rg]);
        }
        if (tid < 16) db[sp ^ 1][tid] = 0.0f;
        __syncthreads();
        const f32x4 d4 = *(const f32x4*)&db[sp][rb];
#pragma unroll
        for (int rg = 0; rg < 4; ++rg) md[rg] = fminf(md[rg], d4[rg]);
      }
    }
  }
  if (w == 0 && l15 == 0)  // q=0..3 cover rows 0..15 (md broadcast-replicated)
    atomicAdd(out, (md[0] + md[1] + md[2] + md[3]) * (1.0f / 4096.0f));
}

}  // namespace

extern "C" void kernel_launch(void* const* d_in, const int* in_sizes, int n_in,
                              void* d_out, int out_size, void* d_ws,
                              size_t ws_size, hipStream_t stream) {
  (void)in_sizes; (void)n_in; (void)out_size; (void)ws_size;
  const float* x_start = (const float*)d_in[0];
  const float* x_end = (const float*)d_in[1];
  const float* noise = (const float*)d_in[2];
  const float* W1 = (const float*)d_in[3];
  const float* b1 = (const float*)d_in[4];
  const float* W2 = (const float*)d_in[5];
  const float* b2 = (const float*)d_in[6];
  const float* Ww1 = (const float*)d_in[7];
  const float* bw1 = (const float*)d_in[8];
  const float* Ww2 = (const float*)d_in[9];
  const float* bw2 = (const float*)d_in[10];
  const float* Wp1 = (const float*)d_in[11];
  const float* bp1 = (const float*)d_in[12];
  const float* wp2 = (const float*)d_in[13];
  float* out = (float*)d_out;

  // workspace layout (~61 MB)
  float* Xf = (float*)d_ws;                        // z_s  4096*256 f32
  float* ZEf = Xf + (size_t)4096 * 256;            // z_e
  short* XSb = (short*)(ZEf + (size_t)4096 * 256); // x bf16 8192*2048
  short* H1b = XSb + (size_t)8192 * 2048;          // enc hidden bf16 8192*1024
  short* W1T = H1b + (size_t)8192 * 1024;          // 1024*2048
  short* W2T = W1T + (size_t)1024 * 2048;          // 256*1024
  short* Ww1T = W2T + (size_t)256 * 1024;
  short* Ww2T = Ww1T + 65536;
  short* WpT = Ww2T + 65536;                       // Wp1^T
  short* Wp1s = WpT + 65536;                       // wp2-scaled Wp1 row-major

  const dim3 blk(256);

  cvt_w<<<2560, blk, 0, stream>>>(W1, W2, Ww1, Ww2, Wp1, wp2, W1T, W2T, Ww1T,
                                  Ww2T, WpT, Wp1s);
  cvt2<<<2048, blk, 0, stream>>>(x_start, x_end, XSb, (long)8192 * 2048);
  gemm128_tanh<<<dim3(8, 64), blk, 0, stream>>>(XSb, W1T, b1, H1b, 8192, 1024,
                                                2048);
  gemm64_enc2<<<dim3(4, 128), blk, 0, stream>>>(H1b, W2T, b2, Xf, ZEf, 8192,
                                                256, 1024);
  hipMemsetAsync(d_out, 0, sizeof(float), stream);
  trace_fused<<<256, dim3(512), 0, stream>>>(Xf, ZEf, noise, WpT, Wp1s, Ww1T,
                                             Ww2T, bw1, bw2, bp1, out);
}

// Round 7
// 325.234 us; speedup vs baseline: 1.1740x; 1.0009x over previous
//
// Round 7: trace barrier diet (12/step: deferred st3 distance read; vv
// reduction hoisted pre-barrier1); prep_all merges input+weight converts;
// gemm64_enc2 at BK=64. 5 dispatches.

#include <hip/hip_runtime.h>
#include <math.h>

typedef short bf8 __attribute__((ext_vector_type(8)));   // 8 bf16 = 4 VGPR
typedef float f32x4 __attribute__((ext_vector_type(4))); // MFMA acc

namespace {

constexpr float H_STEP = 1.0f / 15.0f;

__device__ inline short f2bf(float f) {  // RNE f32 -> bf16
  unsigned u = __float_as_uint(f);
  u += 0x7fffu + ((u >> 16) & 1u);
  return (short)(u >> 16);
}

__device__ inline float fast_tanh(float x) {
  const float ax = fabsf(x);
  const float e = __expf(-2.0f * ax);
  const float t = (1.0f - e) * __builtin_amdgcn_rcpf(1.0f + e);
  return copysignf(t, x);
}

// 1 - tanh(x)^2 = 4 e / (1+e)^2, e = exp(-2|x|)
__device__ inline float sech2(float x) {
  const float e = __expf(-2.0f * fabsf(x));
  const float r = __builtin_amdgcn_rcpf(1.0f + e);
  return 4.0f * e * r * r;
}

__device__ inline float wave_sum(float v) {
#pragma unroll
  for (int sh = 32; sh > 0; sh >>= 1) v += __shfl_xor(v, sh);
  return v;
}

// sum over each 16-lane group via DPP row_ror 1/2/4/8 (VALU-rate butterfly)
template <int CTRL>
__device__ inline float dppadd(float v) {
  return v + __int_as_float(__builtin_amdgcn_update_dpp(
                 0, __float_as_int(v), CTRL, 0xF, 0xF, true));
}
__device__ inline float red16(float v) {
  v = dppadd<0x121>(v);
  v = dppadd<0x122>(v);
  v = dppadd<0x124>(v);
  v = dppadd<0x128>(v);
  return v;
}

// async global->LDS, 16B per lane. LDS dest = wave-uniform base + lane*16.
__device__ inline void async16(const void* g, void* l) {
  __builtin_amdgcn_global_load_lds((__attribute__((address_space(1))) void*)g,
                                   (__attribute__((address_space(3))) void*)l,
                                   16, 0, 0);
}

// ---------------- one-shot prep: inputs + all weight converts ----------------
// blocks [0,2048): x_start/x_end -> XSb [8192][2048] bf16 (grid-stride x8)
// [2048,4096): W1^T  [4096,4352): W2^T  [4352,4416): Ww1^T
// [4416,4480): Ww2^T [4480,4544): Wp1^T [4544,4608): wp2-scaled Wp1 copy
__global__ __launch_bounds__(256) void prep_all(
    const float* __restrict__ xs, const float* __restrict__ xe,
    const float* __restrict__ W1, const float* __restrict__ W2,
    const float* __restrict__ Ww1, const float* __restrict__ Ww2,
    const float* __restrict__ Wp1, const float* __restrict__ wp2,
    short* __restrict__ XSb, short* __restrict__ W1T, short* __restrict__ W2T,
    short* __restrict__ Ww1T, short* __restrict__ Ww2T,
    short* __restrict__ WpT, short* __restrict__ Wp1s) {
  __shared__ float tile[32][33];
  const int id = blockIdx.x;
  if (id < 2048) {
    const long n = (long)8192 * 2048, half = n >> 1;
    long i = ((long)id * 256 + threadIdx.x) * 4;
    const long stride = (long)2048 * 1024;
    for (; i < n; i += stride) {
      const float* s = (i < half) ? (xs + i) : (xe + (i - half));
      const float4 f = *(const float4*)s;
      ushort4 o;
      o.x = (unsigned short)f2bf(f.x);
      o.y = (unsigned short)f2bf(f.y);
      o.z = (unsigned short)f2bf(f.z);
      o.w = (unsigned short)f2bf(f.w);
      *(ushort4*)(XSb + i) = o;
    }
    return;
  }
  const int tr = threadIdx.x >> 5, tc = threadIdx.x & 31;
  const float* src;
  short* dst;
  int K, N, kt, nt;
  if (id < 4096) {
    src = W1; dst = W1T; K = 2048; N = 1024; kt = (id - 2048) >> 5; nt = (id - 2048) & 31;
  } else if (id < 4352) {
    src = W2; dst = W2T; K = 1024; N = 256; kt = (id - 4096) >> 3; nt = (id - 4096) & 7;
  } else if (id < 4416) {
    src = Ww1; dst = Ww1T; K = 256; N = 256; kt = (id - 4352) >> 3; nt = (id - 4352) & 7;
  } else if (id < 4480) {
    src = Ww2; dst = Ww2T; K = 256; N = 256; kt = (id - 4416) >> 3; nt = (id - 4416) & 7;
  } else if (id < 4544) {
    src = Wp1; dst = WpT; K = 256; N = 256; kt = (id - 4480) >> 3; nt = (id - 4480) & 7;
  } else {  // wp2-scaled row-major copy
    const int lid = id - 4544;
    const int k0 = (lid >> 3) * 32, n0 = (lid & 7) * 32;
#pragma unroll
    for (int i = 0; i < 32; i += 8) {
      const size_t o = (size_t)(k0 + tr + i) * 256 + n0 + tc;
      Wp1s[o] = f2bf(Wp1[o] * wp2[n0 + tc]);
    }
    return;
  }
  const int k0 = kt * 32, n0 = nt * 32;
#pragma unroll
  for (int i = 0; i < 32; i += 8)
    tile[tr + i][tc] = src[(size_t)(k0 + tr + i) * N + n0 + tc];
  __syncthreads();
#pragma unroll
  for (int i = 0; i < 32; i += 8)
    dst[(size_t)(n0 + tr + i) * K + k0 + tc] = f2bf(tile[tc][tr + i]);
}

// ---------------- bf16 TN GEMMs, global_load_lds staging ----------------

// 128x128 tile, BK=64, tanh->bf16 epilogue (encoder L1)
__global__ __launch_bounds__(256) void gemm128_tanh(
    const short* __restrict__ A, const short* __restrict__ Bt,
    const float* __restrict__ bias, short* __restrict__ Cb, int M, int N,
    int K) {
  __shared__ __align__(16) short As[2 * 128 * 32];
  __shared__ __align__(16) short Bs[2 * 128 * 32];
  const int tid = threadIdx.x;
  const int w = tid >> 6, lane = tid & 63, q = lane >> 4, l15 = lane & 15;
  const int wm = (w >> 1) * 64, wn = (w & 1) * 64;
  const int m0 = blockIdx.y * 128, n0 = blockIdx.x * 128;
  const f32x4 fzero = {0.0f, 0.0f, 0.0f, 0.0f};
  f32x4 acc[4][4];
#pragma unroll
  for (int mt = 0; mt < 4; ++mt)
#pragma unroll
    for (int nt = 0; nt < 4; ++nt) acc[mt][nt] = fzero;

  for (int k0 = 0; k0 < K; k0 += 64) {
#pragma unroll
    for (int kcb = 0; kcb < 2; ++kcb)
#pragma unroll
      for (int j = 0; j < 2; ++j) {
        const int c = w * 128 + j * 64 + lane;
        async16(A + (size_t)(m0 + (c >> 2)) * K + k0 + kcb * 32 + (c & 3) * 8,
                &As[kcb * 4096 + (w * 128 + j * 64) * 8]);
        async16(Bt + (size_t)(n0 + (c >> 2)) * K + k0 + kcb * 32 + (c & 3) * 8,
                &Bs[kcb * 4096 + (w * 128 + j * 64) * 8]);
      }
    __syncthreads();
#pragma unroll
    for (int kcb = 0; kcb < 2; ++kcb) {
      bf8 af[4], bfr[4];
#pragma unroll
      for (int mt = 0; mt < 4; ++mt)
        af[mt] =
            *(const bf8*)&As[kcb * 4096 + (wm + mt * 16 + l15) * 32 + q * 8];
#pragma unroll
      for (int nt = 0; nt < 4; ++nt)
        bfr[nt] =
            *(const bf8*)&Bs[kcb * 4096 + (wn + nt * 16 + l15) * 32 + q * 8];
#pragma unroll
      for (int mt = 0; mt < 4; ++mt)
#pragma unroll
        for (int nt = 0; nt < 4; ++nt)
          acc[mt][nt] = __builtin_amdgcn_mfma_f32_16x16x32_bf16(
              af[mt], bfr[nt], acc[mt][nt], 0, 0, 0);
    }
    __syncthreads();
  }
#pragma unroll
  for (int mt = 0; mt < 4; ++mt)
#pragma unroll
    for (int nt = 0; nt < 4; ++nt) {
      const int col = n0 + wn + nt * 16 + l15;
      const float bcol = bias[col];
#pragma unroll
      for (int rg = 0; rg < 4; ++rg) {
        const int row = m0 + wm + mt * 16 + q * 4 + rg;
        Cb[(size_t)row * N + col] = f2bf(fast_tanh(acc[mt][nt][rg] + bcol));
      }
    }
}

// 64x64 tile, BK=64; rows<4096 -> z_s, rows>=4096 -> z_e (both f32)
__global__ __launch_bounds__(256) void gemm64_enc2(
    const short* __restrict__ A, const short* __restrict__ Bt,
    const float* __restrict__ bias, float* __restrict__ Zs,
    float* __restrict__ Ze, int M, int N, int K) {
  __shared__ __align__(16) short As[2 * 64 * 32];
  __shared__ __align__(16) short Bs[2 * 64 * 32];
  const int tid = threadIdx.x;
  const int w = tid >> 6, lane = tid & 63, q = lane >> 4, l15 = lane & 15;
  const int wm = (w >> 1) * 32, wn = (w & 1) * 32;
  const int m0 = blockIdx.y * 64, n0 = blockIdx.x * 64;
  const f32x4 fzero = {0.0f, 0.0f, 0.0f, 0.0f};
  f32x4 acc[2][2];
#pragma unroll
  for (int mt = 0; mt < 2; ++mt)
#pragma unroll
    for (int nt = 0; nt < 2; ++nt) acc[mt][nt] = fzero;

  for (int k0 = 0; k0 < K; k0 += 64) {
    const int c = w * 64 + lane;
#pragma unroll
    for (int kcb = 0; kcb < 2; ++kcb) {
      async16(A + (size_t)(m0 + (c >> 2)) * K + k0 + kcb * 32 + (c & 3) * 8,
              &As[kcb * 2048 + (w * 64) * 8]);
      async16(Bt + (size_t)(n0 + (c >> 2)) * K + k0 + kcb * 32 + (c & 3) * 8,
              &Bs[kcb * 2048 + (w * 64) * 8]);
    }
    __syncthreads();
#pragma unroll
    for (int kcb = 0; kcb < 2; ++kcb) {
      bf8 af[2], bfr[2];
#pragma unroll
      for (int mt = 0; mt < 2; ++mt)
        af[mt] =
            *(const bf8*)&As[kcb * 2048 + (wm + mt * 16 + l15) * 32 + q * 8];
#pragma unroll
      for (int nt = 0; nt < 2; ++nt)
        bfr[nt] =
            *(const bf8*)&Bs[kcb * 2048 + (wn + nt * 16 + l15) * 32 + q * 8];
#pragma unroll
      for (int mt = 0; mt < 2; ++mt)
#pragma unroll
        for (int nt = 0; nt < 2; ++nt)
          acc[mt][nt] = __builtin_amdgcn_mfma_f32_16x16x32_bf16(
              af[mt], bfr[nt], acc[mt][nt], 0, 0, 0);
    }
    __syncthreads();
  }
#pragma unroll
  for (int mt = 0; mt < 2; ++mt)
#pragma unroll
    for (int nt = 0; nt < 2; ++nt) {
      const int col = n0 + wn + nt * 16 + l15;
      const float bcol = bias[col];
#pragma unroll
      for (int rg = 0; rg < 4; ++rg) {
        const int row = m0 + wm + mt * 16 + q * 4 + rg;
        const float val = acc[mt][nt][rg] + bcol;
        if (row < 4096)
          Zs[(size_t)row * N + col] = val;
        else
          Ze[(size_t)(row - 4096) * N + col] = val;
      }
    }
}

// ---------------- fused wind + fallback + trace ----------------
// 256 blocks x 512 threads (8 waves, 2/SIMD). Wave w owns cols w*32+t*16+l15.
// 12 barriers/step: st3 distance read deferred past next step's barrier1;
// vv reduction hoisted before barrier1 (only gv remains post-mm2).

__global__ __launch_bounds__(512, 2) void trace_fused(
    const float* __restrict__ Xg, const float* __restrict__ ZEg,
    const float* __restrict__ NZg, const short* __restrict__ WT,
    const short* __restrict__ Wp1s, const short* __restrict__ Ww1T,
    const short* __restrict__ Ww2T, const float* __restrict__ bw1,
    const float* __restrict__ bw2, const float* __restrict__ bp1,
    float* __restrict__ out) {
  constexpr float hs = H_STEP;
  __shared__ __align__(16) short XsL[4096];
  __shared__ __align__(16) short UL[4096];
  __shared__ __align__(16) float gvb[2][16];
  __shared__ __align__(16) float vvb[2][16];
  __shared__ __align__(16) float db[2][16];
  const int tid = threadIdx.x;
  const int w = tid >> 6, lane = tid & 63, q = lane >> 4, l15 = lane & 15;
  const int r0 = blockIdx.x * 16, rb = q * 4;

  if (tid < 16) {
    gvb[0][tid] = 0.0f; gvb[1][tid] = 0.0f;
    vvb[0][tid] = 0.0f; vvb[1][tid] = 0.0f;
    db[0][tid] = 0.0f;  db[1][tid] = 0.0f;
  }

  int cc[2], wadr[2][4], radr[8];
  float bp1c[2], bw1c[2], bw2c[2];
#pragma unroll
  for (int t = 0; t < 2; ++t) {
    const int c = w * 32 + t * 16 + l15;
    cc[t] = c;
    const int kc = c >> 3, cx = kc & 15, cl = c & 7;
#pragma unroll
    for (int rg = 0; rg < 4; ++rg)
      wadr[t][rg] = kc * 128 + ((rb + rg) ^ cx) * 8 + cl;
    bp1c[t] = bp1[c];
    bw1c[t] = bw1[c];
    bw2c[t] = bw2[c];
  }
#pragma unroll
  for (int ks = 0; ks < 8; ++ks) {
    const int kq = ks * 4 + q;
    radr[ks] = (kq * 16 + (l15 ^ (kq & 15))) * 8;
  }
  float x[2][4], ze[2][4], nz[2][4];
#pragma unroll
  for (int t = 0; t < 2; ++t)
#pragma unroll
    for (int rg = 0; rg < 4; ++rg) {
      const size_t off = (size_t)(r0 + rb + rg) * 256 + cc[t];
      x[t][rg] = Xg[off];
      ze[t][rg] = ZEg[off];
      nz[t][rg] = NZg[off];
    }
  const f32x4 fzero = {0.0f, 0.0f, 0.0f, 0.0f};

  // ---- wind MLP + degenerate-wind fallback ----
  float v[2][4];
  {
    bf8 Wf1[2][8], Wf2[2][8];
#pragma unroll
    for (int t = 0; t < 2; ++t)
#pragma unroll
      for (int ks = 0; ks < 8; ++ks) {
        Wf1[t][ks] = *(const bf8*)(Ww1T + cc[t] * 256 + ks * 32 + q * 8);
        Wf2[t][ks] = *(const bf8*)(Ww2T + cc[t] * 256 + ks * 32 + q * 8);
      }
#pragma unroll
    for (int t = 0; t < 2; ++t)
#pragma unroll
      for (int rg = 0; rg < 4; ++rg) XsL[wadr[t][rg]] = f2bf(x[t][rg]);
    __syncthreads();
    bf8 af[8];
#pragma unroll
    for (int ks = 0; ks < 8; ++ks) af[ks] = *(const bf8*)&XsL[radr[ks]];
    f32x4 acc[2];
#pragma unroll
    for (int t = 0; t < 2; ++t) {
      f32x4 a0 = fzero, a1 = fzero;
#pragma unroll
      for (int ks = 0; ks < 8; ks += 2) {
        a0 = __builtin_amdgcn_mfma_f32_16x16x32_bf16(af[ks], Wf1[t][ks], a0,
                                                     0, 0, 0);
        a1 = __builtin_amdgcn_mfma_f32_16x16x32_bf16(af[ks + 1],
                                                     Wf1[t][ks + 1], a1, 0, 0,
                                                     0);
      }
      acc[t] = a0 + a1;
    }
#pragma unroll
    for (int t = 0; t < 2; ++t)
#pragma unroll
      for (int rg = 0; rg < 4; ++rg)
        UL[wadr[t][rg]] = f2bf(fast_tanh(acc[t][rg] + bw1c[t]));
    __syncthreads();
#pragma unroll
    for (int ks = 0; ks < 8; ++ks) af[ks] = *(const bf8*)&UL[radr[ks]];
#pragma unroll
    for (int t = 0; t < 2; ++t) {
      f32x4 a0 = fzero, a1 = fzero;
#pragma unroll
      for (int ks = 0; ks < 8; ks += 2) {
        a0 = __builtin_amdgcn_mfma_f32_16x16x32_bf16(af[ks], Wf2[t][ks], a0,
                                                     0, 0, 0);
        a1 = __builtin_amdgcn_mfma_f32_16x16x32_bf16(af[ks + 1],
                                                     Wf2[t][ks + 1], a1, 0, 0,
                                                     0);
      }
      acc[t] = a0 + a1;
#pragma unroll
      for (int rg = 0; rg < 4; ++rg) v[t][rg] = acc[t][rg] + bw2c[t];
    }
    float pn[4], pm[4];
#pragma unroll
    for (int rg = 0; rg < 4; ++rg) {
      pn[rg] = red16(v[0][rg] * v[0][rg] + v[1][rg] * v[1][rg]);
      pm[rg] = red16(nz[0][rg] * nz[0][rg] + nz[1][rg] * nz[1][rg]);
    }
    if (l15 == 0) {
#pragma unroll
      for (int rg = 0; rg < 4; ++rg) {
        atomicAdd(&gvb[0][rb + rg], pn[rg]);
        atomicAdd(&vvb[0][rb + rg], pm[rg]);
      }
    }
    __syncthreads();
#pragma unroll
    for (int rg = 0; rg < 4; ++rg) {
      const float wn = sqrtf(gvb[0][rb + rg] + 1e-24f);
      const float sc = (wn < 1e-5f)
                           ? 1e-4f / (sqrtf(vvb[0][rb + rg] + 1e-24f) + 1e-12f)
                           : 0.0f;
      v[0][rg] = fmaf(sc, nz[0][rg], v[0][rg]);
      v[1][rg] = fmaf(sc, nz[1][rg], v[1][rg]);
    }
    __syncthreads();
    if (tid < 16) {
      gvb[0][tid] = 0.0f;
      vvb[0][tid] = 0.0f;
    }
    __syncthreads();  // order zeroing before step0's early vv atomics
  }

  // ---- trace weight frags (Wf regs dead, reused by allocator) ----
  bf8 B1f[2][8], B2f[2][8];
#pragma unroll
  for (int t = 0; t < 2; ++t)
#pragma unroll
    for (int ks = 0; ks < 8; ++ks) {
      B1f[t][ks] = *(const bf8*)(WT + cc[t] * 256 + ks * 32 + q * 8);
      B2f[t][ks] = *(const bf8*)(Wp1s + cc[t] * 256 + ks * 32 + q * 8);
    }
  float ap[2][4], xacc[2][4], vacc[2][4], md[4];
#pragma unroll
  for (int rg = 0; rg < 4; ++rg) {
    ap[0][rg] = 0.0f; ap[1][rg] = 0.0f;
    xacc[0][rg] = 0.0f; xacc[1][rg] = 0.0f;
    vacc[0][rg] = 0.0f; vacc[1][rg] = 0.0f;
    md[rg] = 3.4e38f;
  }
  const float cxv_t[4] = {0.0f, 0.5f * hs, 0.5f * hs, hs};
  const float cxa_t[4] = {0.0f, 0.0f, 0.25f * hs * hs, 0.5f * hs * hs};
  const float cva_t[4] = {0.0f, 0.5f * hs, 0.5f * hs, hs};

#pragma unroll 1
  for (int step = 0; step < 15; ++step) {
#pragma unroll
    for (int st = 0; st < 4; ++st) {
      const int p = st & 1;
      const float cxv = cxv_t[st], cxa = cxa_t[st], cva = cva_t[st];
      // A. stage velocity + position; vv reduction hoisted pre-barrier
      float vs[2][4];
#pragma unroll
      for (int t = 0; t < 2; ++t)
#pragma unroll
        for (int rg = 0; rg < 4; ++rg) {
          vs[t][rg] = fmaf(cva, ap[t][rg], v[t][rg]);
          XsL[wadr[t][rg]] =
              f2bf(x[t][rg] + cxv * v[t][rg] + cxa * ap[t][rg]);
        }
      {
        float pv[4];
#pragma unroll
        for (int rg = 0; rg < 4; ++rg)
          pv[rg] = red16(fmaf(vs[0][rg], vs[0][rg], vs[1][rg] * vs[1][rg]));
        if (l15 == 0) {
#pragma unroll
          for (int rg = 0; rg < 4; ++rg) atomicAdd(&vvb[p][rb + rg], pv[rg]);
        }
      }
      __syncthreads();  // B1
      // B. deferred closest-approach read (st0, step>0)
      if (st == 0 && step > 0) {
        const f32x4 d4 = *(const f32x4*)&db[(step - 1) & 1][rb];
#pragma unroll
        for (int rg = 0; rg < 4; ++rg) md[rg] = fminf(md[rg], d4[rg]);
      }
      // mm1: H = Xs @ Wp1
      bf8 af[8];
#pragma unroll
      for (int ks = 0; ks < 8; ++ks) af[ks] = *(const bf8*)&XsL[radr[ks]];
      f32x4 acc[2];
#pragma unroll
      for (int t = 0; t < 2; ++t) {
        f32x4 a0 = fzero, a1 = fzero;
#pragma unroll
        for (int ks = 0; ks < 8; ks += 2) {
          a0 = __builtin_amdgcn_mfma_f32_16x16x32_bf16(af[ks], B1f[t][ks], a0,
                                                       0, 0, 0);
          a1 = __builtin_amdgcn_mfma_f32_16x16x32_bf16(af[ks + 1],
                                                       B1f[t][ks + 1], a1, 0,
                                                       0, 0);
        }
        acc[t] = a0 + a1;
      }
      // U = sech^2 (wp2 absorbed into Wp1s) -> LDS; zero next parity bufs
#pragma unroll
      for (int t = 0; t < 2; ++t)
#pragma unroll
        for (int rg = 0; rg < 4; ++rg)
          UL[wadr[t][rg]] = f2bf(sech2(acc[t][rg] + bp1c[t]));
      if (tid < 16) {
        gvb[p ^ 1][tid] = 0.0f;
        vvb[p ^ 1][tid] = 0.0f;
      }
      __syncthreads();  // B2
      // C. mm2: G = U @ (wp2*Wp1)^T; deferred db zero (post-B2, race-free)
      if (st == 0 && step > 0 && tid < 16) db[(step - 1) & 1][tid] = 0.0f;
#pragma unroll
      for (int ks = 0; ks < 8; ++ks) af[ks] = *(const bf8*)&UL[radr[ks]];
#pragma unroll
      for (int t = 0; t < 2; ++t) {
        f32x4 a0 = fzero, a1 = fzero;
#pragma unroll
        for (int ks = 0; ks < 8; ks += 2) {
          a0 = __builtin_amdgcn_mfma_f32_16x16x32_bf16(af[ks], B2f[t][ks], a0,
                                                       0, 0, 0);
          a1 = __builtin_amdgcn_mfma_f32_16x16x32_bf16(af[ks + 1],
                                                       B2f[t][ks + 1], a1, 0,
                                                       0, 0);
        }
        acc[t] = a0 + a1;
      }
      {
        float pg[4];
#pragma unroll
        for (int rg = 0; rg < 4; ++rg)
          pg[rg] =
              red16(fmaf(acc[0][rg], vs[0][rg], acc[1][rg] * vs[1][rg]));
        if (l15 == 0) {
#pragma unroll
          for (int rg = 0; rg < 4; ++rg) atomicAdd(&gvb[p][rb + rg], pg[rg]);
        }
      }
      __syncthreads();  // B3
      // D. broadcast read + accel + RK4 accumulation
      const f32x4 gv4 = *(const f32x4*)&gvb[p][rb];
      const f32x4 vv4 = *(const f32x4*)&vvb[p][rb];
#pragma unroll
      for (int t = 0; t < 2; ++t)
#pragma unroll
        for (int rg = 0; rg < 4; ++rg) {
          const float a = -gv4[rg] * vs[t][rg] + 0.5f * vv4[rg] * acc[t][rg];
          ap[t][rg] = a;
          if (st == 0) {
            xacc[t][rg] = a;
            vacc[t][rg] = a;
          } else if (st < 3) {
            xacc[t][rg] += a;
            vacc[t][rg] += 2.0f * a;
          } else {
            vacc[t][rg] += a;
          }
        }
      // E. st3: step update + distance partials (read deferred past next B1)
      if (st == 3) {
        const int sp = step & 1;
        float pd[4];
#pragma unroll
        for (int rg = 0; rg < 4; ++rg) {
          float acc_d = 0.0f;
#pragma unroll
          for (int t = 0; t < 2; ++t) {
            const float xn =
                x[t][rg] + hs * v[t][rg] + (hs * hs / 6.0f) * xacc[t][rg];
            const float vn = v[t][rg] + (hs / 6.0f) * vacc[t][rg];
            x[t][rg] = xn;
            v[t][rg] = vn;
            const float d = xn - ze[t][rg];
            acc_d = fmaf(d, d, acc_d);
          }
          pd[rg] = red16(acc_d);
        }
        if (l15 == 0) {
#pragma unroll
          for (int rg = 0; rg < 4; ++rg) atomicAdd(&db[sp][rb + rg], pd[rg]);
        }
      }
    }
  }
  __syncthreads();  // final step's distance atomics
  {
    const f32x4 d4 = *(const f32x4*)&db[14 & 1][rb];
#pragma unroll
    for (int rg = 0; rg < 4; ++rg) md[rg] = fminf(md[rg], d4[rg]);
  }
  if (w == 0 && l15 == 0)  // q=0..3 cover rows 0..15 (md broadcast-replicated)
    atomicAdd(out, (md[0] + md[1] + md[2] + md[3]) * (1.0f / 4096.0f));
}

}  // namespace

extern "C" void kernel_launch(void* const* d_in, const int* in_sizes, int n_in,
                              void* d_out, int out_size, void* d_ws,
                              size_t ws_size, hipStream_t stream) {
  (void)in_sizes; (void)n_in; (void)out_size; (void)ws_size;
  const float* x_start = (const float*)d_in[0];
  const float* x_end = (const float*)d_in[1];
  const float* noise = (const float*)d_in[2];
  const float* W1 = (const float*)d_in[3];
  const float* b1 = (const float*)d_in[4];
  const float* W2 = (const float*)d_in[5];
  const float* b2 = (const float*)d_in[6];
  const float* Ww1 = (const float*)d_in[7];
  const float* bw1 = (const float*)d_in[8];
  const float* Ww2 = (const float*)d_in[9];
  const float* bw2 = (const float*)d_in[10];
  const float* Wp1 = (const float*)d_in[11];
  const float* bp1 = (const float*)d_in[12];
  const float* wp2 = (const float*)d_in[13];
  float* out = (float*)d_out;

  // workspace layout (~61 MB)
  float* Xf = (float*)d_ws;                        // z_s  4096*256 f32
  float* ZEf = Xf + (size_t)4096 * 256;            // z_e
  short* XSb = (short*)(ZEf + (size_t)4096 * 256); // x bf16 8192*2048
  short* H1b = XSb + (size_t)8192 * 2048;          // enc hidden bf16 8192*1024
  short* W1T = H1b + (size_t)8192 * 1024;          // 1024*2048
  short* W2T = W1T + (size_t)1024 * 2048;          // 256*1024
  short* Ww1T = W2T + (size_t)256 * 1024;
  short* Ww2T = Ww1T + 65536;
  short* WpT = Ww2T + 65536;                       // Wp1^T
  short* Wp1s = WpT + 65536;                       // wp2-scaled Wp1 row-major

  const dim3 blk(256);

  prep_all<<<4608, blk, 0, stream>>>(x_start, x_end, W1, W2, Ww1, Ww2, Wp1,
                                     wp2, XSb, W1T, W2T, Ww1T, Ww2T, WpT,
                                     Wp1s);
  gemm128_tanh<<<dim3(8, 64), blk, 0, stream>>>(XSb, W1T, b1, H1b, 8192, 1024,
                                                2048);
  gemm64_enc2<<<dim3(4, 128), blk, 0, stream>>>(H1b, W2T, b2, Xf, ZEf, 8192,
                                                256, 1024);
  hipMemsetAsync(d_out, 0, sizeof(float), stream);
  trace_fused<<<256, dim3(512), 0, stream>>>(Xf, ZEf, noise, WpT, Wp1s, Ww1T,
                                             Ww2T, bw1, bw2, bp1, out);
}